// Round 11
// baseline (777.200 us; speedup 1.0000x reference)
//
#include <hip/hip_runtime.h>
#include <cstdint>
#include <cstddef>

#define N_NODES 100000
#define N_EDGES 3200000
#define MPAD    100096   // 782 * 128
#define HID     256
#define NBUCK   196
#define BSH     9
#define BSTRIDE 18432

typedef _Float16 f16;
typedef _Float16 f16x2 __attribute__((ext_vector_type(2)));
typedef _Float16 f16x8 __attribute__((ext_vector_type(8)));
typedef float    f32x4 __attribute__((ext_vector_type(4)));
typedef float    f32x2 __attribute__((ext_vector_type(2)));
typedef long long i64;

union F16x2 { unsigned u; f16 h[2]; f16x2 v; };
__device__ inline unsigned pack2(float a, float b) {
    F16x2 x; x.h[0] = (f16)a; x.h[1] = (f16)b; return x.u;
}

// ---------------- CSR build: bucketed counting sort ----------------
__global__ __launch_bounds__(256) void k_bucketA(const int* __restrict__ src,
                                                 const int* __restrict__ dst,
                                                 unsigned* __restrict__ pairs,
                                                 int* __restrict__ nb, int e) {
    __shared__ int hist[NBUCK];
    __shared__ int lbase[NBUCK];
    __shared__ int lcur[NBUCK];
    const int t = threadIdx.x;
    for (int i = t; i < NBUCK; i += 256) hist[i] = 0;
    __syncthreads();
    const int e0 = blockIdx.x * 4096;
    bool v[16]; int d[16], s[16];
#pragma unroll
    for (int i = 0; i < 16; ++i) {
        int idx = e0 + i * 256 + t;
        v[i] = idx < e;
        d[i] = v[i] ? dst[idx] : 0;
        s[i] = v[i] ? src[idx] : 0;
    }
#pragma unroll
    for (int i = 0; i < 16; ++i)
        if (v[i]) atomicAdd(&hist[d[i] >> BSH], 1);
    __syncthreads();
    for (int i = t; i < NBUCK; i += 256) {
        int h = hist[i];
        lbase[i] = h ? atomicAdd(&nb[i], h) : 0;
        lcur[i] = 0;
    }
    __syncthreads();
#pragma unroll
    for (int i = 0; i < 16; ++i) {
        if (v[i]) {
            int b = d[i] >> BSH;
            int p = atomicAdd(&lcur[b], 1);
            unsigned packed = ((unsigned)(d[i] & 511) << 17) | (unsigned)s[i];
            pairs[(size_t)b * BSTRIDE + lbase[b] + p] = packed;
        }
    }
}

__global__ void k_scan196(const int* __restrict__ nb, int* __restrict__ bbase,
                          int* __restrict__ rowptrN) {
    __shared__ int s[256];
    int t = threadIdx.x;
    int v = (t < NBUCK) ? nb[t] : 0;
    s[t] = v;
    __syncthreads();
    for (int off = 1; off < 256; off <<= 1) {
        int u = (t >= off) ? s[t - off] : 0;
        __syncthreads();
        s[t] += u;
        __syncthreads();
    }
    if (t < NBUCK) bbase[t] = s[t] - v;
    if (t == 0) *rowptrN = N_EDGES;
}

__global__ __launch_bounds__(256) void k_bucketB(const unsigned* __restrict__ pairs,
                                                 const int* __restrict__ nb,
                                                 const int* __restrict__ bbase,
                                                 int* __restrict__ rowptr,
                                                 int* __restrict__ colidx) {
    __shared__ int deg[512];
    __shared__ int sc[512];
    __shared__ int cur[512];
    const int b = blockIdx.x, t = threadIdx.x;
    const int cnt = nb[b], base = bbase[b];
    const unsigned* P = pairs + (size_t)b * BSTRIDE;
    deg[t] = 0; deg[t + 256] = 0;
    __syncthreads();
    for (int i = t; i < cnt; i += 256) atomicAdd(&deg[P[i] >> 17], 1);
    __syncthreads();
    sc[t] = deg[t]; sc[t + 256] = deg[t + 256];
    __syncthreads();
    for (int off = 1; off < 512; off <<= 1) {
        int a0 = (t >= off) ? sc[t - off] : 0;
        int a1 = (t + 256 >= off) ? sc[t + 256 - off] : 0;
        __syncthreads();
        sc[t] += a0; sc[t + 256] += a1;
        __syncthreads();
    }
    int node0 = b << BSH;
#pragma unroll
    for (int rep = 0; rep < 2; ++rep) {
        int i = t + rep * 256;
        int excl = base + sc[i] - deg[i];
        cur[i] = excl;
        int node = node0 + i;
        if (node < N_NODES) rowptr[node] = excl;
    }
    __syncthreads();
    // colidx stores src*64 (pre-scaled row offset: 64 lanes/row in both tables)
    for (int i = t; i < cnt; i += 256) {
        unsigned p = P[i];
        int pos = atomicAdd(&cur[p >> 17], 1);
        colidx[pos] = (int)(p & 0x1FFFF) << 6;
    }
}

// ---------------- dtype prep ----------------
__global__ void k_cvt8(const float2* __restrict__ x, unsigned short* __restrict__ o, int n) {
    int t = blockIdx.x * 256 + threadIdx.x;
    if (t < n) {
        float2 v = x[t];
        int pk = __builtin_amdgcn_cvt_pk_fp8_f32(v.x, v.y, 0, false);
        o[t] = (unsigned short)(pk & 0xffff);
    }
}

__global__ void k_foldw1(const float* __restrict__ W, const float* __restrict__ b1,
                         const float* __restrict__ gm, const float* __restrict__ bt,
                         const float* __restrict__ mu, const float* __restrict__ vr,
                         f16* __restrict__ Wt, float* __restrict__ bias, int K) {
    int t = blockIdx.x * 256 + threadIdx.x;
    if (t >= K * 256) return;
    int n = t & 255, k = t >> 8;
    float sc = gm[n] * rsqrtf(vr[n] + 1e-5f);
    Wt[n * K + k] = (f16)(W[t] * sc);
    if (k == 0) bias[n] = (b1[n] - mu[n]) * sc + bt[n];
}

// W2 f32 [k][n] -> fp8 e4m3 transposed [n][256], scaled x8 (recenters e4m3 range;
// pairs with Ys = y/8 so the product y*W2 is exact-scale)
__global__ void k_transb8(const float* __restrict__ W, unsigned char* __restrict__ W8) {
    int t = blockIdx.x * 256 + threadIdx.x;   // 65536
    int n = t & 255, k = t >> 8;
    float v = W[t] * 8.f;
    int pk = __builtin_amdgcn_cvt_pk_fp8_f32(v, v, 0, false);
    W8[n * 256 + k] = (unsigned char)(pk & 0xff);
}

// W2o[k][o] = sum_j W2[k][j]*outW[j][o]; bo[o] = sum_j b2[j]*outW[j][o] + outb[o]
__global__ void k_fold2(const float* __restrict__ W2, const float* __restrict__ b2,
                        const float* __restrict__ outW, const float* __restrict__ outb,
                        float* __restrict__ W2o, float* __restrict__ bo) {
    int k = threadIdx.x;
    float a0 = 0.f, a1 = 0.f;
    for (int j = 0; j < 256; ++j) {
        float w = W2[k * 256 + j];
        a0 += w * outW[j * 2 + 0];
        a1 += w * outW[j * 2 + 1];
    }
    W2o[k * 2 + 0] = a0;
    W2o[k * 2 + 1] = a1;
    if (k < 2) {
        float b = outb[k];
        for (int j = 0; j < 256; ++j) b += b2[j] * outW[j * 2 + k];
        bo[k] = b;
    }
}

// ---------------- aggregation ----------------
// h8 stores fp8(h/8): dequant scale x8 applied once at the end.
__global__ void k_agg256(const unsigned* __restrict__ h8,
                         const int* __restrict__ rp, const int* __restrict__ ci,
                         uint2* __restrict__ z, int n) {
    int gw = (blockIdx.x * 256 + threadIdx.x) >> 6;
    if (gw >= n) return;
    int lane = threadIdx.x & 63;
    const unsigned* h8l = h8 + lane;
    f32x2 A01, A23;
    {
        unsigned u = h8l[(size_t)gw * 64];
        A01 = __builtin_amdgcn_cvt_pk_f32_fp8(u, false);
        A23 = __builtin_amdgcn_cvt_pk_f32_fp8(u, true);
    }
    int s = rp[gw], e = rp[gw + 1];
    int p = s;
    for (; p + 7 < e; p += 8) {
        int j0 = ci[p],     j1 = ci[p + 1], j2 = ci[p + 2], j3 = ci[p + 3];
        int j4 = ci[p + 4], j5 = ci[p + 5], j6 = ci[p + 6], j7 = ci[p + 7];
        unsigned u0 = h8l[(size_t)j0], u1 = h8l[(size_t)j1];
        unsigned u2 = h8l[(size_t)j2], u3 = h8l[(size_t)j3];
        unsigned u4 = h8l[(size_t)j4], u5 = h8l[(size_t)j5];
        unsigned u6 = h8l[(size_t)j6], u7 = h8l[(size_t)j7];
#pragma unroll
        for (int q = 0; q < 8; ++q) {
            unsigned u = q == 0 ? u0 : q == 1 ? u1 : q == 2 ? u2 : q == 3 ? u3
                       : q == 4 ? u4 : q == 5 ? u5 : q == 6 ? u6 : u7;
            A01 += __builtin_amdgcn_cvt_pk_f32_fp8(u, false);
            A23 += __builtin_amdgcn_cvt_pk_f32_fp8(u, true);
        }
    }
    for (; p < e; ++p) {
        unsigned u = h8l[(size_t)ci[p]];
        A01 += __builtin_amdgcn_cvt_pk_f32_fp8(u, false);
        A23 += __builtin_amdgcn_cvt_pk_f32_fp8(u, true);
    }
    uint2 o;
    o.x = pack2(A01[0] * 8.f, A01[1] * 8.f);
    o.y = pack2(A23[0] * 8.f, A23[1] * 8.f);
    z[(size_t)gw * 64 + lane] = o;
}

__global__ void k_agg128(const unsigned short* __restrict__ x8,
                         const int* __restrict__ rp, const int* __restrict__ ci,
                         unsigned* __restrict__ z, int n) {
    int gw = (blockIdx.x * 256 + threadIdx.x) >> 6;
    if (gw >= n) return;
    int lane = threadIdx.x & 63;
    const unsigned short* xl = x8 + lane;
    f32x2 A01 = __builtin_amdgcn_cvt_pk_f32_fp8((unsigned)xl[(size_t)gw * 64], false);
    int s = rp[gw], e = rp[gw + 1];
    int p = s;
    for (; p + 7 < e; p += 8) {
        int j0 = ci[p],     j1 = ci[p + 1], j2 = ci[p + 2], j3 = ci[p + 3];
        int j4 = ci[p + 4], j5 = ci[p + 5], j6 = ci[p + 6], j7 = ci[p + 7];
        unsigned u0 = xl[(size_t)j0], u1 = xl[(size_t)j1];
        unsigned u2 = xl[(size_t)j2], u3 = xl[(size_t)j3];
        unsigned u4 = xl[(size_t)j4], u5 = xl[(size_t)j5];
        unsigned u6 = xl[(size_t)j6], u7 = xl[(size_t)j7];
        A01 += __builtin_amdgcn_cvt_pk_f32_fp8(u0, false);
        A01 += __builtin_amdgcn_cvt_pk_f32_fp8(u1, false);
        A01 += __builtin_amdgcn_cvt_pk_f32_fp8(u2, false);
        A01 += __builtin_amdgcn_cvt_pk_f32_fp8(u3, false);
        A01 += __builtin_amdgcn_cvt_pk_f32_fp8(u4, false);
        A01 += __builtin_amdgcn_cvt_pk_f32_fp8(u5, false);
        A01 += __builtin_amdgcn_cvt_pk_f32_fp8(u6, false);
        A01 += __builtin_amdgcn_cvt_pk_f32_fp8(u7, false);
    }
    for (; p < e; ++p)
        A01 += __builtin_amdgcn_cvt_pk_f32_fp8((unsigned)xl[(size_t)ci[p]], false);
    z[(size_t)gw * 64 + lane] = pack2(A01[0], A01[1]);
}

// ---------------- fused layer: h8 = fp8(relu(relu(z@W1+b1)@W2+b2)/8) ----------------
// LDS: As 16K + (Bs|Ys union) 32K = 48K -> 3 blocks/CU. ni-loops chunked (bfv[4])
// to fit the 3-waves/EU VGPR budget (~170).
template <int K>
__global__ __launch_bounds__(256, 3) void k_layer(const f16* __restrict__ A,
                                                  const f16* __restrict__ W1,
                                                  const float* __restrict__ b1,
                                                  const unsigned char* __restrict__ W28,
                                                  const float* __restrict__ b2,
                                                  unsigned char* __restrict__ H8) {
    __shared__ f16 As[128 * 64];                       // 16 KB (phase2: W28 region)
    __shared__ __align__(16) char BsYs[32 * 1024];     // Bs (phase1) | Ys (phase2)
    f16* Bs = (f16*)BsYs;
    unsigned char* Ys = (unsigned char*)BsYs;
    const int tid = threadIdx.x;
    const int bm0 = blockIdx.x * 128;
    const int lane = tid & 63, wave = tid >> 6;
    const int quad = lane >> 4, l16 = lane & 15;
    const int wr = (wave >> 1) * 64;
    const int wc = (wave & 1) * 128;
    const f16* Abase = A + (size_t)bm0 * K;

    f32x4 acc[4][8] = {};
    // ---- phase 1: f16 GEMM ----
    for (int k0 = 0; k0 < K; k0 += 64) {
#pragma unroll
        for (int i = 0; i < 4; ++i) {
            int c = i * 256 + tid;
            int m = c >> 3;
            int gg = (c & 7) ^ (m & 7);
            __builtin_amdgcn_global_load_lds(
                (const __attribute__((address_space(1))) unsigned int*)(Abase + (size_t)m * K + k0 + gg * 8),
                (__attribute__((address_space(3))) unsigned int*)(As + (size_t)c * 8), 16, 0, 0);
        }
#pragma unroll
        for (int i = 0; i < 8; ++i) {
            int c = i * 256 + tid;
            int m = c >> 3;
            int gg = (c & 7) ^ (m & 7);
            __builtin_amdgcn_global_load_lds(
                (const __attribute__((address_space(1))) unsigned int*)(W1 + (size_t)m * K + k0 + gg * 8),
                (__attribute__((address_space(3))) unsigned int*)(Bs + (size_t)c * 8), 16, 0, 0);
        }
        __syncthreads();
#pragma unroll
        for (int kk = 0; kk < 64; kk += 32) {
            const int gbase = kk >> 3;
            f16x8 af[4];
#pragma unroll
            for (int mi = 0; mi < 4; ++mi) {
                int m = wr + mi * 16 + l16;
                int slot = (gbase + quad) ^ (m & 7);
                af[mi] = *(const f16x8*)&As[(m * 8 + slot) * 8];
            }
#pragma unroll
            for (int hh = 0; hh < 2; ++hh) {
                f16x8 bfv[4];
#pragma unroll
                for (int nj = 0; nj < 4; ++nj) {
                    int m = wc + (hh * 4 + nj) * 16 + l16;
                    int slot = (gbase + quad) ^ (m & 7);
                    bfv[nj] = *(const f16x8*)&Bs[(m * 8 + slot) * 8];
                }
#pragma unroll
                for (int mi = 0; mi < 4; ++mi)
#pragma unroll
                    for (int nj = 0; nj < 4; ++nj)
                        acc[mi][hh * 4 + nj] = __builtin_amdgcn_mfma_f32_16x16x32_f16(af[mi], bfv[nj], acc[mi][hh * 4 + nj], 0, 0, 0);
            }
        }
        __syncthreads();
    }
    // epilogue: y = relu(acc + b1); Ys = fp8(y/8) swizzled (aliases Bs — safe:
    // the loop's final barrier drained all Bs reads)
    {
        float bv[8];
#pragma unroll
        for (int ni = 0; ni < 8; ++ni) bv[ni] = b1[wc + ni * 16 + l16];
#pragma unroll
        for (int mi = 0; mi < 4; ++mi) {
#pragma unroll
            for (int r = 0; r < 4; ++r) {
                int row = wr + mi * 16 + quad * 4 + r;
#pragma unroll
                for (int ni = 0; ni < 8; ++ni) {
                    float v = fmaxf(acc[mi][ni][r] + bv[ni], 0.f) * 0.125f;
                    int col = wc + ni * 16 + l16;
                    int pk = __builtin_amdgcn_cvt_pk_fp8_f32(v, v, 0, false);
                    int g = col >> 3, j = col & 7;
                    Ys[row * 256 + ((g ^ (row & 15)) * 8 + j)] = (unsigned char)(pk & 0xff);
                }
            }
        }
    }
    __syncthreads();

    // ---- phase 2: fp8 GEMM (K2 = 256); acc2 = (y/8)*(8*W2) = y*W2 ----
    unsigned char* B8 = (unsigned char*)As;
    f32x4 acc2[4][8] = {};
    for (int k0 = 0; k0 < 256; k0 += 64) {
#pragma unroll
        for (int i = 0; i < 4; ++i) {
            int c = i * 256 + tid;
            int n = c >> 2;
            int cg = c & 3;
            int gg = cg ^ (n & 3);
            __builtin_amdgcn_global_load_lds(
                (const __attribute__((address_space(1))) unsigned int*)(W28 + (size_t)n * 256 + k0 + gg * 16),
                (__attribute__((address_space(3))) unsigned int*)(B8 + (size_t)c * 16), 16, 0, 0);
        }
        __syncthreads();
#pragma unroll
        for (int kk = 0; kk < 64; kk += 32) {
            int gq = (kk >> 3) + quad;
            int gglob = ((k0 + kk) >> 3) + quad;
            i64 af[4];
#pragma unroll
            for (int mi = 0; mi < 4; ++mi) {
                int m = wr + mi * 16 + l16;
                af[mi] = *(const i64*)&Ys[m * 256 + ((gglob ^ (m & 15)) * 8)];
            }
#pragma unroll
            for (int hh = 0; hh < 2; ++hh) {
                i64 bf[4];
#pragma unroll
                for (int nj = 0; nj < 4; ++nj) {
                    int n = wc + (hh * 4 + nj) * 16 + l16;
                    int cg2 = gq >> 1, sub = gq & 1;
                    bf[nj] = *(const i64*)&B8[n * 64 + (cg2 ^ (n & 3)) * 16 + sub * 8];
                }
#pragma unroll
                for (int mi = 0; mi < 4; ++mi)
#pragma unroll
                    for (int nj = 0; nj < 4; ++nj)
                        acc2[mi][hh * 4 + nj] = __builtin_amdgcn_mfma_f32_16x16x32_fp8_fp8(af[mi], bf[nj], acc2[mi][hh * 4 + nj], 0, 0, 0);
            }
        }
        __syncthreads();
    }
    // epilogue: h8 = fp8(relu(acc2 + b2)/8)
    float bv2[8];
#pragma unroll
    for (int ni = 0; ni < 8; ++ni) bv2[ni] = b2[wc + ni * 16 + l16];
#pragma unroll
    for (int mi = 0; mi < 4; ++mi) {
#pragma unroll
        for (int r = 0; r < 4; ++r) {
            size_t row = (size_t)(bm0 + wr + mi * 16 + quad * 4 + r);
#pragma unroll
            for (int ni = 0; ni < 8; ++ni) {
                float v = fmaxf(acc2[mi][ni][r] + bv2[ni], 0.f) * 0.125f;
                int col = wc + ni * 16 + l16;
                int pk = __builtin_amdgcn_cvt_pk_fp8_f32(v, v, 0, false);
                H8[row * HID + col] = (unsigned char)(pk & 0xff);
            }
        }
    }
}

// ---------------- fused layer 3: out = relu(z@W1+b1) @ W2o + bo ----------------
__global__ __launch_bounds__(256, 3) void k_layer3(const f16* __restrict__ A,
                                                   const f16* __restrict__ W1,
                                                   const float* __restrict__ b1,
                                                   const float* __restrict__ W2o,
                                                   const float* __restrict__ bo,
                                                   float* __restrict__ out) {
    __shared__ f16 As[128 * 64];
    __shared__ f16 Bs[256 * 64];
    __shared__ float W2s[512];
    __shared__ float ob[256];    // [128 rows][2]
    const int tid = threadIdx.x;
    const int bm0 = blockIdx.x * 128;
    const int lane = tid & 63, wave = tid >> 6;
    const int quad = lane >> 4, l16 = lane & 15;
    const int wr = (wave >> 1) * 64;
    const int wc = (wave & 1) * 128;
    const f16* Abase = A + (size_t)bm0 * 256;
    W2s[tid] = W2o[tid];
    W2s[tid + 256] = W2o[tid + 256];
    ob[tid] = 0.f;

    f32x4 acc[4][8] = {};
    for (int k0 = 0; k0 < 256; k0 += 64) {
#pragma unroll
        for (int i = 0; i < 4; ++i) {
            int c = i * 256 + tid;
            int m = c >> 3;
            int gg = (c & 7) ^ (m & 7);
            __builtin_amdgcn_global_load_lds(
                (const __attribute__((address_space(1))) unsigned int*)(Abase + (size_t)m * 256 + k0 + gg * 8),
                (__attribute__((address_space(3))) unsigned int*)(As + (size_t)c * 8), 16, 0, 0);
        }
#pragma unroll
        for (int i = 0; i < 8; ++i) {
            int c = i * 256 + tid;
            int m = c >> 3;
            int gg = (c & 7) ^ (m & 7);
            __builtin_amdgcn_global_load_lds(
                (const __attribute__((address_space(1))) unsigned int*)(W1 + (size_t)m * 256 + k0 + gg * 8),
                (__attribute__((address_space(3))) unsigned int*)(Bs + (size_t)c * 8), 16, 0, 0);
        }
        __syncthreads();
#pragma unroll
        for (int kk = 0; kk < 64; kk += 32) {
            const int gbase = kk >> 3;
            f16x8 af[4];
#pragma unroll
            for (int mi = 0; mi < 4; ++mi) {
                int m = wr + mi * 16 + l16;
                int slot = (gbase + quad) ^ (m & 7);
                af[mi] = *(const f16x8*)&As[(m * 8 + slot) * 8];
            }
#pragma unroll
            for (int hh = 0; hh < 2; ++hh) {
                f16x8 bfv[4];
#pragma unroll
                for (int nj = 0; nj < 4; ++nj) {
                    int m = wc + (hh * 4 + nj) * 16 + l16;
                    int slot = (gbase + quad) ^ (m & 7);
                    bfv[nj] = *(const f16x8*)&Bs[(m * 8 + slot) * 8];
                }
#pragma unroll
                for (int mi = 0; mi < 4; ++mi)
#pragma unroll
                    for (int nj = 0; nj < 4; ++nj)
                        acc[mi][hh * 4 + nj] = __builtin_amdgcn_mfma_f32_16x16x32_f16(af[mi], bfv[nj], acc[mi][hh * 4 + nj], 0, 0, 0);
            }
        }
        __syncthreads();
    }
    // head: per-row partial dot with W2o, reduce across l16, accumulate in LDS
    float bv[8];
#pragma unroll
    for (int ni = 0; ni < 8; ++ni) bv[ni] = b1[wc + ni * 16 + l16];
#pragma unroll
    for (int mi = 0; mi < 4; ++mi) {
#pragma unroll
        for (int r = 0; r < 4; ++r) {
            int row = wr + mi * 16 + quad * 4 + r;
            float p0 = 0.f, p1 = 0.f;
#pragma unroll
            for (int ni = 0; ni < 8; ++ni) {
                float v = fmaxf(acc[mi][ni][r] + bv[ni], 0.f);
                int col = wc + ni * 16 + l16;
                p0 += v * W2s[col * 2 + 0];
                p1 += v * W2s[col * 2 + 1];
            }
#pragma unroll
            for (int off = 1; off <= 8; off <<= 1) {
                p0 += __shfl_xor(p0, off);
                p1 += __shfl_xor(p1, off);
            }
            if (l16 == 0) {
                atomicAdd(&ob[row * 2 + 0], p0);
                atomicAdd(&ob[row * 2 + 1], p1);
            }
        }
    }
    __syncthreads();
    int row = tid >> 1, o = tid & 1;
    if (bm0 + row < N_NODES)
        out[(size_t)(bm0 + row) * 2 + o] = ob[tid] + bo[o];
}

extern "C" void kernel_launch(void* const* d_in, const int* in_sizes, int n_in,
                              void* d_out, int out_size, void* d_ws, size_t ws_size,
                              hipStream_t stream) {
    const float* x    = (const float*)d_in[0];
    const int*   ei   = (const int*)d_in[1];
    const int*   esrc = ei;
    const int*   edst = ei + N_EDGES;
    const float* lw[3][8];
    for (int l = 0; l < 3; ++l)
        for (int j = 0; j < 8; ++j) lw[l][j] = (const float*)d_in[2 + l * 8 + j];
    const float* outW = (const float*)d_in[26];
    const float* outB = (const float*)d_in[27];

    char* base = (char*)d_ws;
    size_t off = 0;
    auto alloc = [&](size_t bytes) -> void* {
        void* r = base + off;
        off += (bytes + 255) & ~(size_t)255;
        return r;
    };
    f16* z  = (f16*)alloc((size_t)MPAD * 256 * 2);
    unsigned char* h8 = (unsigned char*)alloc((size_t)MPAD * 256);
    unsigned short* x8 = (unsigned short*)alloc((size_t)MPAD * 64 * 2);
    f16* W1t[3]; float* bias1[3]; unsigned char* W28[2];
    W1t[0] = (f16*)alloc(256 * 128 * 2);
    W1t[1] = (f16*)alloc(256 * 256 * 2);
    W1t[2] = (f16*)alloc(256 * 256 * 2);
    for (int l = 0; l < 2; ++l) W28[l] = (unsigned char*)alloc(256 * 256);
    for (int l = 0; l < 3; ++l) bias1[l] = (float*)alloc(256 * 4);
    float* W2o = (float*)alloc(512 * 4);
    float* bo  = (float*)alloc(2 * 4);
    unsigned* pairs = (unsigned*)alloc((size_t)NBUCK * BSTRIDE * 4);
    int* nb     = (int*)alloc(NBUCK * 4);
    int* bbase  = (int*)alloc(NBUCK * 4);
    int* rowptr = (int*)alloc((size_t)(N_NODES + 1) * 4);
    int* colidx = (int*)alloc((size_t)N_EDGES * 4);

    // CSR build
    hipMemsetAsync(nb, 0, NBUCK * 4, stream);
    k_bucketA<<<(N_EDGES + 4095) / 4096, 256, 0, stream>>>(esrc, edst, pairs, nb, N_EDGES);
    k_scan196<<<1, 256, 0, stream>>>(nb, bbase, rowptr + N_NODES);
    k_bucketB<<<NBUCK, 256, 0, stream>>>(pairs, nb, bbase, rowptr, colidx);

    // dtype prep + weight folds
    k_cvt8<<<(N_NODES * 64 + 255) / 256, 256, 0, stream>>>((const float2*)x, x8, N_NODES * 64);
    k_foldw1<<<128, 256, 0, stream>>>(lw[0][0], lw[0][1], lw[0][2], lw[0][3], lw[0][4], lw[0][5], W1t[0], bias1[0], 128);
    k_foldw1<<<256, 256, 0, stream>>>(lw[1][0], lw[1][1], lw[1][2], lw[1][3], lw[1][4], lw[1][5], W1t[1], bias1[1], 256);
    k_foldw1<<<256, 256, 0, stream>>>(lw[2][0], lw[2][1], lw[2][2], lw[2][3], lw[2][4], lw[2][5], W1t[2], bias1[2], 256);
    k_transb8<<<256, 256, 0, stream>>>(lw[0][6], W28[0]);
    k_transb8<<<256, 256, 0, stream>>>(lw[1][6], W28[1]);
    k_fold2<<<1, 256, 0, stream>>>(lw[2][6], lw[2][7], outW, outB, W2o, bo);

    const int GG = MPAD / 128;
    const int WBLOCKS = (N_NODES + 3) / 4;

    // layer 1
    k_agg128<<<WBLOCKS, 256, 0, stream>>>(x8, rowptr, colidx, (unsigned*)z, N_NODES);
    k_layer<128><<<GG, 256, 0, stream>>>(z, W1t[0], bias1[0], W28[0], lw[0][7], h8);
    // layer 2
    k_agg256<<<WBLOCKS, 256, 0, stream>>>((const unsigned*)h8, rowptr, colidx, (uint2*)z, N_NODES);
    k_layer<256><<<GG, 256, 0, stream>>>(z, W1t[1], bias1[1], W28[1], lw[1][7], h8);
    // layer 3 (fused GEMM1 + head)
    k_agg256<<<WBLOCKS, 256, 0, stream>>>((const unsigned*)h8, rowptr, colidx, (uint2*)z, N_NODES);
    k_layer3<<<GG, 256, 0, stream>>>(z, W1t[2], bias1[2], W2o, bo, (float*)d_out);
}

// Round 12
// 683.708 us; speedup vs baseline: 1.1367x; 1.1367x over previous
//
#include <hip/hip_runtime.h>
#include <cstdint>
#include <cstddef>

#define N_NODES 100000
#define N_EDGES 3200000
#define MPAD    100096   // 782 * 128
#define HID     256
#define NBUCK   196
#define BSH     9
#define BSTRIDE 18432

typedef _Float16 f16;
typedef _Float16 f16x2 __attribute__((ext_vector_type(2)));
typedef _Float16 f16x8 __attribute__((ext_vector_type(8)));
typedef float    f32x4 __attribute__((ext_vector_type(4)));
typedef float    f32x2 __attribute__((ext_vector_type(2)));
typedef long long i64;

union F16x2 { unsigned u; f16 h[2]; f16x2 v; };
__device__ inline unsigned pack2(float a, float b) {
    F16x2 x; x.h[0] = (f16)a; x.h[1] = (f16)b; return x.u;
}

// ---------------- CSR build: bucketed counting sort ----------------
__global__ __launch_bounds__(256) void k_bucketA(const int* __restrict__ src,
                                                 const int* __restrict__ dst,
                                                 unsigned* __restrict__ pairs,
                                                 int* __restrict__ nb, int e) {
    __shared__ int hist[NBUCK];
    __shared__ int lbase[NBUCK];
    __shared__ int lcur[NBUCK];
    const int t = threadIdx.x;
    for (int i = t; i < NBUCK; i += 256) hist[i] = 0;
    __syncthreads();
    const int e0 = blockIdx.x * 4096;
    bool v[16]; int d[16], s[16];
#pragma unroll
    for (int i = 0; i < 16; ++i) {
        int idx = e0 + i * 256 + t;
        v[i] = idx < e;
        d[i] = v[i] ? dst[idx] : 0;
        s[i] = v[i] ? src[idx] : 0;
    }
#pragma unroll
    for (int i = 0; i < 16; ++i)
        if (v[i]) atomicAdd(&hist[d[i] >> BSH], 1);
    __syncthreads();
    for (int i = t; i < NBUCK; i += 256) {
        int h = hist[i];
        lbase[i] = h ? atomicAdd(&nb[i], h) : 0;
        lcur[i] = 0;
    }
    __syncthreads();
#pragma unroll
    for (int i = 0; i < 16; ++i) {
        if (v[i]) {
            int b = d[i] >> BSH;
            int p = atomicAdd(&lcur[b], 1);
            unsigned packed = ((unsigned)(d[i] & 511) << 17) | (unsigned)s[i];
            pairs[(size_t)b * BSTRIDE + lbase[b] + p] = packed;
        }
    }
}

__global__ void k_scan196(const int* __restrict__ nb, int* __restrict__ bbase,
                          int* __restrict__ rowptrN) {
    __shared__ int s[256];
    int t = threadIdx.x;
    int v = (t < NBUCK) ? nb[t] : 0;
    s[t] = v;
    __syncthreads();
    for (int off = 1; off < 256; off <<= 1) {
        int u = (t >= off) ? s[t - off] : 0;
        __syncthreads();
        s[t] += u;
        __syncthreads();
    }
    if (t < NBUCK) bbase[t] = s[t] - v;
    if (t == 0) *rowptrN = N_EDGES;
}

__global__ __launch_bounds__(256) void k_bucketB(const unsigned* __restrict__ pairs,
                                                 const int* __restrict__ nb,
                                                 const int* __restrict__ bbase,
                                                 int* __restrict__ rowptr,
                                                 int* __restrict__ colidx) {
    __shared__ int deg[512];
    __shared__ int sc[512];
    __shared__ int cur[512];
    const int b = blockIdx.x, t = threadIdx.x;
    const int cnt = nb[b], base = bbase[b];
    const unsigned* P = pairs + (size_t)b * BSTRIDE;
    deg[t] = 0; deg[t + 256] = 0;
    __syncthreads();
    for (int i = t; i < cnt; i += 256) atomicAdd(&deg[P[i] >> 17], 1);
    __syncthreads();
    sc[t] = deg[t]; sc[t + 256] = deg[t + 256];
    __syncthreads();
    for (int off = 1; off < 512; off <<= 1) {
        int a0 = (t >= off) ? sc[t - off] : 0;
        int a1 = (t + 256 >= off) ? sc[t + 256 - off] : 0;
        __syncthreads();
        sc[t] += a0; sc[t + 256] += a1;
        __syncthreads();
    }
    int node0 = b << BSH;
#pragma unroll
    for (int rep = 0; rep < 2; ++rep) {
        int i = t + rep * 256;
        int excl = base + sc[i] - deg[i];
        cur[i] = excl;
        int node = node0 + i;
        if (node < N_NODES) rowptr[node] = excl;
    }
    __syncthreads();
    // colidx stores src*64 (pre-scaled row offset: 64 lanes/row in both tables)
    for (int i = t; i < cnt; i += 256) {
        unsigned p = P[i];
        int pos = atomicAdd(&cur[p >> 17], 1);
        colidx[pos] = (int)(p & 0x1FFFF) << 6;
    }
}

// ---------------- dtype prep ----------------
__global__ void k_cvt8(const float2* __restrict__ x, unsigned short* __restrict__ o, int n) {
    int t = blockIdx.x * 256 + threadIdx.x;
    if (t < n) {
        float2 v = x[t];
        int pk = __builtin_amdgcn_cvt_pk_fp8_f32(v.x, v.y, 0, false);
        o[t] = (unsigned short)(pk & 0xffff);
    }
}

__global__ void k_foldw1(const float* __restrict__ W, const float* __restrict__ b1,
                         const float* __restrict__ gm, const float* __restrict__ bt,
                         const float* __restrict__ mu, const float* __restrict__ vr,
                         f16* __restrict__ Wt, float* __restrict__ bias, int K) {
    int t = blockIdx.x * 256 + threadIdx.x;
    if (t >= K * 256) return;
    int n = t & 255, k = t >> 8;
    float sc = gm[n] * rsqrtf(vr[n] + 1e-5f);
    Wt[n * K + k] = (f16)(W[t] * sc);
    if (k == 0) bias[n] = (b1[n] - mu[n]) * sc + bt[n];
}

// W2 f32 [k][n] -> fp8 e4m3 transposed [n][256]
__global__ void k_transb8(const float* __restrict__ W, unsigned char* __restrict__ W8) {
    int t = blockIdx.x * 256 + threadIdx.x;   // 65536
    int n = t & 255, k = t >> 8;
    float v = W[t];
    int pk = __builtin_amdgcn_cvt_pk_fp8_f32(v, v, 0, false);
    W8[n * 256 + k] = (unsigned char)(pk & 0xff);
}

// W2o[k][o] = sum_j W2[k][j]*outW[j][o]; bo[o] = sum_j b2[j]*outW[j][o] + outb[o]
__global__ void k_fold2(const float* __restrict__ W2, const float* __restrict__ b2,
                        const float* __restrict__ outW, const float* __restrict__ outb,
                        float* __restrict__ W2o, float* __restrict__ bo) {
    int k = threadIdx.x;
    float a0 = 0.f, a1 = 0.f;
    for (int j = 0; j < 256; ++j) {
        float w = W2[k * 256 + j];
        a0 += w * outW[j * 2 + 0];
        a1 += w * outW[j * 2 + 1];
    }
    W2o[k * 2 + 0] = a0;
    W2o[k * 2 + 1] = a1;
    if (k < 2) {
        float b = outb[k];
        for (int j = 0; j < 256; ++j) b += b2[j] * outW[j * 2 + k];
        bo[k] = b;
    }
}

// ---------------- aggregation ----------------
__global__ void k_agg256(const unsigned* __restrict__ h8,
                         const int* __restrict__ rp, const int* __restrict__ ci,
                         uint2* __restrict__ z, int n) {
    int gw = (blockIdx.x * 256 + threadIdx.x) >> 6;
    if (gw >= n) return;
    int lane = threadIdx.x & 63;
    const unsigned* h8l = h8 + lane;
    f32x2 A01, A23;
    {
        unsigned u = h8l[(size_t)gw * 64];
        A01 = __builtin_amdgcn_cvt_pk_f32_fp8(u, false);
        A23 = __builtin_amdgcn_cvt_pk_f32_fp8(u, true);
    }
    int s = rp[gw], e = rp[gw + 1];
    int p = s;
    for (; p + 7 < e; p += 8) {
        int j0 = ci[p],     j1 = ci[p + 1], j2 = ci[p + 2], j3 = ci[p + 3];
        int j4 = ci[p + 4], j5 = ci[p + 5], j6 = ci[p + 6], j7 = ci[p + 7];
        unsigned u0 = h8l[(size_t)j0], u1 = h8l[(size_t)j1];
        unsigned u2 = h8l[(size_t)j2], u3 = h8l[(size_t)j3];
        unsigned u4 = h8l[(size_t)j4], u5 = h8l[(size_t)j5];
        unsigned u6 = h8l[(size_t)j6], u7 = h8l[(size_t)j7];
#pragma unroll
        for (int q = 0; q < 8; ++q) {
            unsigned u = q == 0 ? u0 : q == 1 ? u1 : q == 2 ? u2 : q == 3 ? u3
                       : q == 4 ? u4 : q == 5 ? u5 : q == 6 ? u6 : u7;
            A01 += __builtin_amdgcn_cvt_pk_f32_fp8(u, false);
            A23 += __builtin_amdgcn_cvt_pk_f32_fp8(u, true);
        }
    }
    for (; p < e; ++p) {
        unsigned u = h8l[(size_t)ci[p]];
        A01 += __builtin_amdgcn_cvt_pk_f32_fp8(u, false);
        A23 += __builtin_amdgcn_cvt_pk_f32_fp8(u, true);
    }
    uint2 o; o.x = pack2(A01[0], A01[1]); o.y = pack2(A23[0], A23[1]);
    z[(size_t)gw * 64 + lane] = o;
}

__global__ void k_agg128(const unsigned short* __restrict__ x8,
                         const int* __restrict__ rp, const int* __restrict__ ci,
                         unsigned* __restrict__ z, int n) {
    int gw = (blockIdx.x * 256 + threadIdx.x) >> 6;
    if (gw >= n) return;
    int lane = threadIdx.x & 63;
    const unsigned short* xl = x8 + lane;
    f32x2 A01 = __builtin_amdgcn_cvt_pk_f32_fp8((unsigned)xl[(size_t)gw * 64], false);
    int s = rp[gw], e = rp[gw + 1];
    int p = s;
    for (; p + 7 < e; p += 8) {
        int j0 = ci[p],     j1 = ci[p + 1], j2 = ci[p + 2], j3 = ci[p + 3];
        int j4 = ci[p + 4], j5 = ci[p + 5], j6 = ci[p + 6], j7 = ci[p + 7];
        unsigned u0 = xl[(size_t)j0], u1 = xl[(size_t)j1];
        unsigned u2 = xl[(size_t)j2], u3 = xl[(size_t)j3];
        unsigned u4 = xl[(size_t)j4], u5 = xl[(size_t)j5];
        unsigned u6 = xl[(size_t)j6], u7 = xl[(size_t)j7];
        A01 += __builtin_amdgcn_cvt_pk_f32_fp8(u0, false);
        A01 += __builtin_amdgcn_cvt_pk_f32_fp8(u1, false);
        A01 += __builtin_amdgcn_cvt_pk_f32_fp8(u2, false);
        A01 += __builtin_amdgcn_cvt_pk_f32_fp8(u3, false);
        A01 += __builtin_amdgcn_cvt_pk_f32_fp8(u4, false);
        A01 += __builtin_amdgcn_cvt_pk_f32_fp8(u5, false);
        A01 += __builtin_amdgcn_cvt_pk_f32_fp8(u6, false);
        A01 += __builtin_amdgcn_cvt_pk_f32_fp8(u7, false);
    }
    for (; p < e; ++p)
        A01 += __builtin_amdgcn_cvt_pk_f32_fp8((unsigned)xl[(size_t)ci[p]], false);
    z[(size_t)gw * 64 + lane] = pack2(A01[0], A01[1]);
}

// ---------------- fused layer: h8 = relu(relu(z@W1+b1)@W2+b2) ----------------
// (256,2): 80 KB LDS, unconstrained VGPRs — R11's (256,3) caused spills.
template <int K>
__global__ __launch_bounds__(256, 2) void k_layer(const f16* __restrict__ A,
                                                  const f16* __restrict__ W1,
                                                  const float* __restrict__ b1,
                                                  const unsigned char* __restrict__ W28,
                                                  const float* __restrict__ b2,
                                                  unsigned char* __restrict__ H8) {
    __shared__ f16 As[128 * 64];            // 16 KB (phase2: W28 chunk region)
    __shared__ f16 Bs[256 * 64];            // 32 KB
    __shared__ unsigned char Ys[128 * 256]; // 32 KB (y fp8)
    const int tid = threadIdx.x;
    const int bm0 = blockIdx.x * 128;
    const int lane = tid & 63, wave = tid >> 6;
    const int quad = lane >> 4, l16 = lane & 15;
    const int wr = (wave >> 1) * 64;
    const int wc = (wave & 1) * 128;
    const f16* Abase = A + (size_t)bm0 * K;

    // ---- phase 1: f16 GEMM ----
    {
        f32x4 acc[4][8] = {};
        for (int k0 = 0; k0 < K; k0 += 64) {
#pragma unroll
            for (int i = 0; i < 4; ++i) {
                int c = i * 256 + tid;
                int m = c >> 3;
                int gg = (c & 7) ^ (m & 7);
                __builtin_amdgcn_global_load_lds(
                    (const __attribute__((address_space(1))) unsigned int*)(Abase + (size_t)m * K + k0 + gg * 8),
                    (__attribute__((address_space(3))) unsigned int*)(As + (size_t)c * 8), 16, 0, 0);
            }
#pragma unroll
            for (int i = 0; i < 8; ++i) {
                int c = i * 256 + tid;
                int m = c >> 3;
                int gg = (c & 7) ^ (m & 7);
                __builtin_amdgcn_global_load_lds(
                    (const __attribute__((address_space(1))) unsigned int*)(W1 + (size_t)m * K + k0 + gg * 8),
                    (__attribute__((address_space(3))) unsigned int*)(Bs + (size_t)c * 8), 16, 0, 0);
            }
            __syncthreads();
#pragma unroll
            for (int kk = 0; kk < 64; kk += 32) {
                const int gbase = kk >> 3;
                f16x8 af[4], bfv[8];
#pragma unroll
                for (int mi = 0; mi < 4; ++mi) {
                    int m = wr + mi * 16 + l16;
                    int slot = (gbase + quad) ^ (m & 7);
                    af[mi] = *(const f16x8*)&As[(m * 8 + slot) * 8];
                }
#pragma unroll
                for (int ni = 0; ni < 8; ++ni) {
                    int m = wc + ni * 16 + l16;
                    int slot = (gbase + quad) ^ (m & 7);
                    bfv[ni] = *(const f16x8*)&Bs[(m * 8 + slot) * 8];
                }
#pragma unroll
                for (int mi = 0; mi < 4; ++mi)
#pragma unroll
                    for (int ni = 0; ni < 8; ++ni)
                        acc[mi][ni] = __builtin_amdgcn_mfma_f32_16x16x32_f16(af[mi], bfv[ni], acc[mi][ni], 0, 0, 0);
            }
            __syncthreads();
        }
        // epilogue: y = relu(acc + b1) -> fp8 into Ys (swizzled)
        float bv[8];
#pragma unroll
        for (int ni = 0; ni < 8; ++ni) bv[ni] = b1[wc + ni * 16 + l16];
#pragma unroll
        for (int mi = 0; mi < 4; ++mi) {
#pragma unroll
            for (int r = 0; r < 4; ++r) {
                int row = wr + mi * 16 + quad * 4 + r;   // block-relative
#pragma unroll
                for (int ni = 0; ni < 8; ++ni) {
                    float v = fmaxf(acc[mi][ni][r] + bv[ni], 0.f);
                    int col = wc + ni * 16 + l16;
                    int pk = __builtin_amdgcn_cvt_pk_fp8_f32(v, v, 0, false);
                    int g = col >> 3, j = col & 7;
                    Ys[row * 256 + ((g ^ (row & 15)) * 8 + j)] = (unsigned char)(pk & 0xff);
                }
            }
        }
    }
    __syncthreads();

    // ---- phase 2: fp8 GEMM (K2 = 256) ----
    unsigned char* B8 = (unsigned char*)As;
    f32x4 acc2[4][8] = {};
    for (int k0 = 0; k0 < 256; k0 += 64) {
#pragma unroll
        for (int i = 0; i < 4; ++i) {       // 1024 chunks of 16 B: W28[n][64 per chunk]
            int c = i * 256 + tid;
            int n = c >> 2;
            int cg = c & 3;
            int gg = cg ^ (n & 3);
            __builtin_amdgcn_global_load_lds(
                (const __attribute__((address_space(1))) unsigned int*)(W28 + (size_t)n * 256 + k0 + gg * 16),
                (__attribute__((address_space(3))) unsigned int*)(B8 + (size_t)c * 16), 16, 0, 0);
        }
        __syncthreads();
#pragma unroll
        for (int kk = 0; kk < 64; kk += 32) {
            int gq = (kk >> 3) + quad;              // local k-group 0..7
            int gglob = ((k0 + kk) >> 3) + quad;    // global k-group 0..31
            i64 af[4], bf[8];
#pragma unroll
            for (int mi = 0; mi < 4; ++mi) {
                int m = wr + mi * 16 + l16;
                af[mi] = *(const i64*)&Ys[m * 256 + ((gglob ^ (m & 15)) * 8)];
            }
#pragma unroll
            for (int ni = 0; ni < 8; ++ni) {
                int n = wc + ni * 16 + l16;
                int cg2 = gq >> 1, sub = gq & 1;
                bf[ni] = *(const i64*)&B8[n * 64 + (cg2 ^ (n & 3)) * 16 + sub * 8];
            }
#pragma unroll
            for (int mi = 0; mi < 4; ++mi)
#pragma unroll
                for (int ni = 0; ni < 8; ++ni)
                    acc2[mi][ni] = __builtin_amdgcn_mfma_f32_16x16x32_fp8_fp8(af[mi], bf[ni], acc2[mi][ni], 0, 0, 0);
        }
        __syncthreads();
    }
    // epilogue: h8 = fp8(relu(acc2 + b2))
    float bv2[8];
#pragma unroll
    for (int ni = 0; ni < 8; ++ni) bv2[ni] = b2[wc + ni * 16 + l16];
#pragma unroll
    for (int mi = 0; mi < 4; ++mi) {
#pragma unroll
        for (int r = 0; r < 4; ++r) {
            size_t row = (size_t)(bm0 + wr + mi * 16 + quad * 4 + r);
#pragma unroll
            for (int ni = 0; ni < 8; ++ni) {
                float v = fmaxf(acc2[mi][ni][r] + bv2[ni], 0.f);
                int col = wc + ni * 16 + l16;
                int pk = __builtin_amdgcn_cvt_pk_fp8_f32(v, v, 0, false);
                H8[row * HID + col] = (unsigned char)(pk & 0xff);
            }
        }
    }
}

// ---------------- fused layer 3: out = relu(z@W1+b1) @ W2o + bo ----------------
__global__ __launch_bounds__(256, 2) void k_layer3(const f16* __restrict__ A,
                                                   const f16* __restrict__ W1,
                                                   const float* __restrict__ b1,
                                                   const float* __restrict__ W2o,
                                                   const float* __restrict__ bo,
                                                   float* __restrict__ out) {
    __shared__ f16 As[128 * 64];
    __shared__ f16 Bs[256 * 64];
    __shared__ float W2s[512];
    __shared__ float ob[256];    // [128 rows][2]
    const int tid = threadIdx.x;
    const int bm0 = blockIdx.x * 128;
    const int lane = tid & 63, wave = tid >> 6;
    const int quad = lane >> 4, l16 = lane & 15;
    const int wr = (wave >> 1) * 64;
    const int wc = (wave & 1) * 128;
    const f16* Abase = A + (size_t)bm0 * 256;
    W2s[tid] = W2o[tid];
    W2s[tid + 256] = W2o[tid + 256];
    ob[tid] = 0.f;

    f32x4 acc[4][8] = {};
    for (int k0 = 0; k0 < 256; k0 += 64) {
#pragma unroll
        for (int i = 0; i < 4; ++i) {
            int c = i * 256 + tid;
            int m = c >> 3;
            int gg = (c & 7) ^ (m & 7);
            __builtin_amdgcn_global_load_lds(
                (const __attribute__((address_space(1))) unsigned int*)(Abase + (size_t)m * 256 + k0 + gg * 8),
                (__attribute__((address_space(3))) unsigned int*)(As + (size_t)c * 8), 16, 0, 0);
        }
#pragma unroll
        for (int i = 0; i < 8; ++i) {
            int c = i * 256 + tid;
            int m = c >> 3;
            int gg = (c & 7) ^ (m & 7);
            __builtin_amdgcn_global_load_lds(
                (const __attribute__((address_space(1))) unsigned int*)(W1 + (size_t)m * 256 + k0 + gg * 8),
                (__attribute__((address_space(3))) unsigned int*)(Bs + (size_t)c * 8), 16, 0, 0);
        }
        __syncthreads();
#pragma unroll
        for (int kk = 0; kk < 64; kk += 32) {
            const int gbase = kk >> 3;
            f16x8 af[4], bfv[8];
#pragma unroll
            for (int mi = 0; mi < 4; ++mi) {
                int m = wr + mi * 16 + l16;
                int slot = (gbase + quad) ^ (m & 7);
                af[mi] = *(const f16x8*)&As[(m * 8 + slot) * 8];
            }
#pragma unroll
            for (int ni = 0; ni < 8; ++ni) {
                int m = wc + ni * 16 + l16;
                int slot = (gbase + quad) ^ (m & 7);
                bfv[ni] = *(const f16x8*)&Bs[(m * 8 + slot) * 8];
            }
#pragma unroll
            for (int mi = 0; mi < 4; ++mi)
#pragma unroll
                for (int ni = 0; ni < 8; ++ni)
                    acc[mi][ni] = __builtin_amdgcn_mfma_f32_16x16x32_f16(af[mi], bfv[ni], acc[mi][ni], 0, 0, 0);
        }
        __syncthreads();
    }
    // head: per-row partial dot with W2o, reduce across l16, accumulate in LDS
    float bv[8];
#pragma unroll
    for (int ni = 0; ni < 8; ++ni) bv[ni] = b1[wc + ni * 16 + l16];
#pragma unroll
    for (int mi = 0; mi < 4; ++mi) {
#pragma unroll
        for (int r = 0; r < 4; ++r) {
            int row = wr + mi * 16 + quad * 4 + r;   // block-relative
            float p0 = 0.f, p1 = 0.f;
#pragma unroll
            for (int ni = 0; ni < 8; ++ni) {
                float v = fmaxf(acc[mi][ni][r] + bv[ni], 0.f);
                int col = wc + ni * 16 + l16;
                p0 += v * W2s[col * 2 + 0];
                p1 += v * W2s[col * 2 + 1];
            }
#pragma unroll
            for (int off = 1; off <= 8; off <<= 1) {
                p0 += __shfl_xor(p0, off);
                p1 += __shfl_xor(p1, off);
            }
            if (l16 == 0) {
                atomicAdd(&ob[row * 2 + 0], p0);
                atomicAdd(&ob[row * 2 + 1], p1);
            }
        }
    }
    __syncthreads();
    int row = tid >> 1, o = tid & 1;
    if (bm0 + row < N_NODES)
        out[(size_t)(bm0 + row) * 2 + o] = ob[tid] + bo[o];
}

extern "C" void kernel_launch(void* const* d_in, const int* in_sizes, int n_in,
                              void* d_out, int out_size, void* d_ws, size_t ws_size,
                              hipStream_t stream) {
    const float* x    = (const float*)d_in[0];
    const int*   ei   = (const int*)d_in[1];
    const int*   esrc = ei;
    const int*   edst = ei + N_EDGES;
    const float* lw[3][8];
    for (int l = 0; l < 3; ++l)
        for (int j = 0; j < 8; ++j) lw[l][j] = (const float*)d_in[2 + l * 8 + j];
    const float* outW = (const float*)d_in[26];
    const float* outB = (const float*)d_in[27];

    char* base = (char*)d_ws;
    size_t off = 0;
    auto alloc = [&](size_t bytes) -> void* {
        void* r = base + off;
        off += (bytes + 255) & ~(size_t)255;
        return r;
    };
    f16* z  = (f16*)alloc((size_t)MPAD * 256 * 2);
    unsigned char* h8 = (unsigned char*)alloc((size_t)MPAD * 256);
    unsigned short* x8 = (unsigned short*)alloc((size_t)MPAD * 64 * 2);
    f16* W1t[3]; float* bias1[3]; unsigned char* W28[2];
    W1t[0] = (f16*)alloc(256 * 128 * 2);
    W1t[1] = (f16*)alloc(256 * 256 * 2);
    W1t[2] = (f16*)alloc(256 * 256 * 2);
    for (int l = 0; l < 2; ++l) W28[l] = (unsigned char*)alloc(256 * 256);
    for (int l = 0; l < 3; ++l) bias1[l] = (float*)alloc(256 * 4);
    float* W2o = (float*)alloc(512 * 4);
    float* bo  = (float*)alloc(2 * 4);
    unsigned* pairs = (unsigned*)alloc((size_t)NBUCK * BSTRIDE * 4);
    int* nb     = (int*)alloc(NBUCK * 4);
    int* bbase  = (int*)alloc(NBUCK * 4);
    int* rowptr = (int*)alloc((size_t)(N_NODES + 1) * 4);
    int* colidx = (int*)alloc((size_t)N_EDGES * 4);

    // CSR build
    hipMemsetAsync(nb, 0, NBUCK * 4, stream);
    k_bucketA<<<(N_EDGES + 4095) / 4096, 256, 0, stream>>>(esrc, edst, pairs, nb, N_EDGES);
    k_scan196<<<1, 256, 0, stream>>>(nb, bbase, rowptr + N_NODES);
    k_bucketB<<<NBUCK, 256, 0, stream>>>(pairs, nb, bbase, rowptr, colidx);

    // dtype prep + weight folds
    k_cvt8<<<(N_NODES * 64 + 255) / 256, 256, 0, stream>>>((const float2*)x, x8, N_NODES * 64);
    k_foldw1<<<128, 256, 0, stream>>>(lw[0][0], lw[0][1], lw[0][2], lw[0][3], lw[0][4], lw[0][5], W1t[0], bias1[0], 128);
    k_foldw1<<<256, 256, 0, stream>>>(lw[1][0], lw[1][1], lw[1][2], lw[1][3], lw[1][4], lw[1][5], W1t[1], bias1[1], 256);
    k_foldw1<<<256, 256, 0, stream>>>(lw[2][0], lw[2][1], lw[2][2], lw[2][3], lw[2][4], lw[2][5], W1t[2], bias1[2], 256);
    k_transb8<<<256, 256, 0, stream>>>(lw[0][6], W28[0]);
    k_transb8<<<256, 256, 0, stream>>>(lw[1][6], W28[1]);
    k_fold2<<<1, 256, 0, stream>>>(lw[2][6], lw[2][7], outW, outB, W2o, bo);

    const int GG = MPAD / 128;
    const int WBLOCKS = (N_NODES + 3) / 4;

    // layer 1
    k_agg128<<<WBLOCKS, 256, 0, stream>>>(x8, rowptr, colidx, (unsigned*)z, N_NODES);
    k_layer<128><<<GG, 256, 0, stream>>>(z, W1t[0], bias1[0], W28[0], lw[0][7], h8);
    // layer 2
    k_agg256<<<WBLOCKS, 256, 0, stream>>>((const unsigned*)h8, rowptr, colidx, (uint2*)z, N_NODES);
    k_layer<256><<<GG, 256, 0, stream>>>(z, W1t[1], bias1[1], W28[1], lw[1][7], h8);
    // layer 3 (fused GEMM1 + head)
    k_agg256<<<WBLOCKS, 256, 0, stream>>>((const unsigned*)h8, rowptr, colidx, (uint2*)z, N_NODES);
    k_layer3<<<GG, 256, 0, stream>>>(z, W1t[2], bias1[2], W2o, bo, (float*)d_out);
}